// Round 1
// baseline (361.073 us; speedup 1.0000x reference)
//
#include <hip/hip_runtime.h>

typedef __attribute__((ext_vector_type(8))) short bf16x8;
typedef __attribute__((ext_vector_type(4))) float f32x4;

__device__ __forceinline__ short f2bf(float f) {
    union { float f; unsigned u; } v; v.f = f;
    unsigned r = (v.u + 0x7FFFu + ((v.u >> 16) & 1u)) >> 16;  // RNE
    return (short)r;
}

__device__ __forceinline__ float sigmoidf(float x) {
    return 1.0f / (1.0f + __expf(-x));
}

constexpr int S = 200, E = 128, A = 64;
constexpr int BSTR = 132;   // padded fp32 stride for behaviors tile rows in LDS
constexpr int WSTR = 136;   // padded bf16 stride for WbT rows in LDS

__global__ __launch_bounds__(256, 3) void attn_fused(
    const float* __restrict__ behaviors,
    const float* __restrict__ target,
    const float* __restrict__ W1,
    const float* __restrict__ b1,
    const float* __restrict__ W2,
    const float* __restrict__ b2,
    float* __restrict__ out)
{
    __shared__ float b_lds[64 * BSTR];   // 33792 B; reused as reduction buffer
    __shared__ short wb_lds[A * WSTR];   // 17408 B
    __shared__ float t_lds[E];
    __shared__ float bias_lds[A];
    __shared__ float w2_lds[A];
    __shared__ float w_lds[64];

    const int tid  = threadIdx.x;
    const int bat  = blockIdx.x;
    const int lane = tid & 63;
    const int wave = tid >> 6;
    const int l15  = lane & 15;
    const int quad = lane >> 4;

    if (tid < E) t_lds[tid] = target[(size_t)bat * E + tid];
    __syncthreads();

    // Per-batch effective weight WbT[a][e] = W1a + W1d + t[e]*W1c, bf16, a-major
    for (int i = tid; i < E * A; i += 256) {
        const int e = i >> 6, a = i & 63;
        const float wa = W1[e * A + a];
        const float wd = W1[(384 + e) * A + a];
        const float wc = W1[(256 + e) * A + a];
        wb_lds[a * WSTR + e] = f2bf(wa + wd + t_lds[e] * wc);
    }
    // Per-batch bias: b1 + t @ (W1b - W1d); stash W2 too
    if (tid < A) {
        float acc = b1[tid];
        for (int e = 0; e < E; ++e)
            acc += t_lds[e] * (W1[(128 + e) * A + tid] - W1[(384 + e) * A + tid]);
        bias_lds[tid] = acc;
        w2_lds[tid] = W2[tid];
    }
    __syncthreads();

    // B fragments (K=128 x N=64) cached in registers; invariant over s.
    // B[k][n]: n = lane&15 (+nt*16), k = quad*8+j (+kt*32)
    bf16x8 bfrag[4][4];
    #pragma unroll
    for (int kt = 0; kt < 4; ++kt)
        #pragma unroll
        for (int nt = 0; nt < 4; ++nt)
            bfrag[kt][nt] = *(const bf16x8*)&wb_lds[(nt*16 + l15) * WSTR + kt*32 + quad*8];

    float bias_l[4], w2_l[4];
    #pragma unroll
    for (int nt = 0; nt < 4; ++nt) {
        bias_l[nt] = bias_lds[nt*16 + l15];
        w2_l[nt]   = w2_lds[nt*16 + l15];
    }
    const float b2v = b2[0];

    const float* bptr = behaviors + (size_t)bat * S * E;
    const int c4  = tid & 31;   // float4 column: e = c4*4
    const int grp = tid >> 5;   // 0..7 -> rows grp*8 .. grp*8+7 each round
    f32x4 oacc = {0.f, 0.f, 0.f, 0.f};

    for (int r = 0; r < 4; ++r) {
        // ---- stage 64 rows of behaviors (fp32, zero-padded past S) ----
        #pragma unroll
        for (int j = 0; j < 8; ++j) {
            const int i   = tid + j * 256;
            const int row = i >> 5;
            const int col = i & 31;
            const int srow = r * 64 + row;
            f32x4 v = {0.f, 0.f, 0.f, 0.f};
            if (srow < S) v = *(const f32x4*)(bptr + srow * E + col * 4);
            *(f32x4*)&b_lds[row * BSTR + col * 4] = v;
        }
        __syncthreads();

        // ---- h = relu(b @ Wb + bias) via MFMA; logit -> w = sigmoid ----
        f32x4 acc[4];
        #pragma unroll
        for (int nt = 0; nt < 4; ++nt) acc[nt] = f32x4{0.f, 0.f, 0.f, 0.f};

        const float* arow = &b_lds[(wave*16 + l15) * BSTR + quad*8];
        #pragma unroll
        for (int kt = 0; kt < 4; ++kt) {
            f32x4 a0 = *(const f32x4*)(arow + kt*32);
            f32x4 a1 = *(const f32x4*)(arow + kt*32 + 4);
            bf16x8 af;
            af[0] = f2bf(a0[0]); af[1] = f2bf(a0[1]);
            af[2] = f2bf(a0[2]); af[3] = f2bf(a0[3]);
            af[4] = f2bf(a1[0]); af[5] = f2bf(a1[1]);
            af[6] = f2bf(a1[2]); af[7] = f2bf(a1[3]);
            #pragma unroll
            for (int nt = 0; nt < 4; ++nt)
                acc[nt] = __builtin_amdgcn_mfma_f32_16x16x32_bf16(af, bfrag[kt][nt], acc[nt], 0, 0, 0);
        }

        // C layout: row = quad*4+reg (s within wave tile), col = nt*16 + l15 (a)
        float wgt[4];
        #pragma unroll
        for (int reg = 0; reg < 4; ++reg) {
            float p = 0.f;
            #pragma unroll
            for (int nt = 0; nt < 4; ++nt) {
                float h = acc[nt][reg] + bias_l[nt];
                p += fmaxf(h, 0.f) * w2_l[nt];
            }
            // reduce across the 16 lanes of this quad (sum over all 64 a)
            #pragma unroll
            for (int off = 1; off < 16; off <<= 1)
                p += __shfl_xor(p, off, 64);
            wgt[reg] = sigmoidf(p + b2v);
        }
        if (l15 == 0) {
            #pragma unroll
            for (int reg = 0; reg < 4; ++reg)
                w_lds[wave*16 + quad*4 + reg] = wgt[reg];
        }
        __syncthreads();

        // ---- out += w_s * behaviors_s (fp32 from LDS) ----
        f32x4 w0 = *(const f32x4*)&w_lds[grp*8];
        f32x4 w1v = *(const f32x4*)&w_lds[grp*8 + 4];
        #pragma unroll
        for (int s = 0; s < 8; ++s) {
            const float w = (s < 4) ? w0[s] : w1v[s - 4];
            f32x4 bv = *(const f32x4*)&b_lds[(grp*8 + s) * BSTR + c4*4];
            oacc[0] += w * bv[0]; oacc[1] += w * bv[1];
            oacc[2] += w * bv[2]; oacc[3] += w * bv[3];
        }
        __syncthreads();   // b_lds reused next round / as red buffer
    }

    // ---- cross-group reduction: 8 partial f32x4 per e-range -> out ----
    float* red = b_lds;
    *(f32x4*)&red[grp * 128 + c4*4] = oacc;
    __syncthreads();
    if (tid < 128) {
        float s = 0.f;
        #pragma unroll
        for (int g = 0; g < 8; ++g) s += red[g * 128 + tid];
        out[(size_t)bat * E + tid] = s;
    }
}

extern "C" void kernel_launch(void* const* d_in, const int* in_sizes, int n_in,
                              void* d_out, int out_size, void* d_ws, size_t ws_size,
                              hipStream_t stream) {
    const float* behaviors = (const float*)d_in[0];
    const float* target    = (const float*)d_in[1];
    const float* W1        = (const float*)d_in[2];
    const float* b1        = (const float*)d_in[3];
    const float* W2        = (const float*)d_in[4];
    const float* b2        = (const float*)d_in[5];
    float* out = (float*)d_out;

    hipLaunchKernelGGL(attn_fused, dim3(2048), dim3(256), 0, stream,
                       behaviors, target, W1, b1, W2, b2, out);
}

// Round 2
// 355.074 us; speedup vs baseline: 1.0169x; 1.0169x over previous
//
#include <hip/hip_runtime.h>

typedef __attribute__((ext_vector_type(8))) short bf16x8;
typedef __attribute__((ext_vector_type(4))) float f32x4;

__device__ __forceinline__ short f2bf(float f) {
    union { float f; unsigned u; } v; v.f = f;
    unsigned r = (v.u + 0x7FFFu + ((v.u >> 16) & 1u)) >> 16;  // RNE
    return (short)r;
}

__device__ __forceinline__ float sigmoidf(float x) {
    return 1.0f / (1.0f + __expf(-x));
}

constexpr int S = 200, E = 128, A = 64;
constexpr int NSTRIP = 13;   // ceil(200/16)

// Wb fragment-linear LDS layout: frag (kt,nt) at [(kt*4+nt)*512 + lane*8 + j]
// (shorts). Lane-contiguous ds_read_b128 -> conflict-free.
__global__ __launch_bounds__(256, 4) void attn_fused(
    const float* __restrict__ behaviors,
    const float* __restrict__ target,
    const float* __restrict__ W1,
    const float* __restrict__ b1,
    const float* __restrict__ W2,
    const float* __restrict__ b2,
    float* __restrict__ out)
{
    __shared__ short wb_f[16 * 512];   // 16 KB, frag-linear bf16 Wb
    __shared__ short wbtmp[E * A];     // 16 KB, [e][a] bf16 staging
    __shared__ float red[4 * 128];     // 2 KB, bias partials / final out partials
    __shared__ float t_lds[E];
    __shared__ float bias_lds[A];
    __shared__ float w2_lds[A];

    const int tid  = threadIdx.x;
    const int bat  = blockIdx.x;
    const int lane = tid & 63;
    const int wave = tid >> 6;
    const int l15  = lane & 15;
    const int quad = lane >> 4;

    if (tid < E) t_lds[tid] = target[(size_t)bat * E + tid];
    __syncthreads();

    // ---- Wb[e][a] = W1a + W1d + t[e]*W1c (bf16) ----
    for (int i = tid; i < E * A; i += 256) {
        const int e = i >> 6, a = i & 63;
        wbtmp[i] = f2bf(W1[e * A + a] + W1[(384 + e) * A + a]
                        + t_lds[e] * W1[(256 + e) * A + a]);
    }
    // ---- bias partials: b1 + t @ (W1b - W1d), split e into 4 segments ----
    {
        const int a = tid & 63, seg = tid >> 6;
        float acc = 0.f;
        for (int e = seg * 32; e < seg * 32 + 32; ++e)
            acc += t_lds[e] * (W1[(128 + e) * A + a] - W1[(384 + e) * A + a]);
        red[seg * 64 + a] = acc;
    }
    __syncthreads();
    if (tid < A) {
        bias_lds[tid] = b1[tid] + red[tid] + red[64 + tid] + red[128 + tid] + red[192 + tid];
        w2_lds[tid] = W2[tid];
    }
    // ---- rearrange Wb into fragment-linear layout ----
    for (int i = tid; i < E * A; i += 256) {
        const int j = i & 7, ln = (i >> 3) & 63, frag = i >> 9;
        const int kt = frag >> 2, nt = frag & 3;
        const int n = nt * 16 + (ln & 15);
        const int k = kt * 32 + (ln >> 4) * 8 + j;
        wb_f[i] = wbtmp[k * A + n];
    }
    __syncthreads();

    float bias_l[4], w2_l[4];
    #pragma unroll
    for (int nt = 0; nt < 4; ++nt) {
        bias_l[nt] = bias_lds[nt * 16 + l15];
        w2_l[nt]   = w2_lds[nt * 16 + l15];
    }
    const float b2v = b2[0];
    const float* bptr = behaviors + (size_t)bat * S * E;

    // ---- barrier-free per-wave strip loop ----
    f32x4 oacc[4][2];
    #pragma unroll
    for (int kt = 0; kt < 4; ++kt) {
        oacc[kt][0] = f32x4{0.f, 0.f, 0.f, 0.f};
        oacc[kt][1] = f32x4{0.f, 0.f, 0.f, 0.f};
    }

    for (int st = wave; st < NSTRIP; st += 4) {
        const int row = st * 16 + l15;
        const bool valid = (row < S);
        const float* rp = bptr + (size_t)row * E + quad * 8;

        f32x4 av[4][2];
        #pragma unroll
        for (int kt = 0; kt < 4; ++kt) {
            av[kt][0] = f32x4{0.f, 0.f, 0.f, 0.f};
            av[kt][1] = f32x4{0.f, 0.f, 0.f, 0.f};
        }
        if (valid) {
            #pragma unroll
            for (int kt = 0; kt < 4; ++kt) {
                av[kt][0] = *(const f32x4*)(rp + kt * 32);
                av[kt][1] = *(const f32x4*)(rp + kt * 32 + 4);
            }
        }

        f32x4 acc[4];
        #pragma unroll
        for (int nt = 0; nt < 4; ++nt) acc[nt] = f32x4{0.f, 0.f, 0.f, 0.f};

        #pragma unroll
        for (int kt = 0; kt < 4; ++kt) {
            bf16x8 af;
            af[0] = f2bf(av[kt][0][0]); af[1] = f2bf(av[kt][0][1]);
            af[2] = f2bf(av[kt][0][2]); af[3] = f2bf(av[kt][0][3]);
            af[4] = f2bf(av[kt][1][0]); af[5] = f2bf(av[kt][1][1]);
            af[6] = f2bf(av[kt][1][2]); af[7] = f2bf(av[kt][1][3]);
            #pragma unroll
            for (int nt = 0; nt < 4; ++nt) {
                bf16x8 bf = *(const bf16x8*)&wb_f[(kt * 4 + nt) * 512 + lane * 8];
                acc[nt] = __builtin_amdgcn_mfma_f32_16x16x32_bf16(af, bf, acc[nt], 0, 0, 0);
            }
        }

        // logits: C row = quad*4+reg, col = nt*16+l15; reduce over 16 a-lanes
        float wgt[4];
        #pragma unroll
        for (int reg = 0; reg < 4; ++reg) {
            float p = 0.f;
            #pragma unroll
            for (int nt = 0; nt < 4; ++nt) {
                const float h = acc[nt][reg] + bias_l[nt];
                p += fmaxf(h, 0.f) * w2_l[nt];
            }
            p += __shfl_xor(p, 1, 64);
            p += __shfl_xor(p, 2, 64);
            p += __shfl_xor(p, 4, 64);
            p += __shfl_xor(p, 8, 64);
            wgt[reg] = sigmoidf(p + b2v);
        }

        // my row's weight: row base+l15 lives in quad l15>>2, element l15&3
        const int srcl = (l15 >> 2) << 4;
        const float t0 = __shfl(wgt[0], srcl, 64);
        const float t1 = __shfl(wgt[1], srcl, 64);
        const float t2 = __shfl(wgt[2], srcl, 64);
        const float t3 = __shfl(wgt[3], srcl, 64);
        const float wl = (l15 & 2) ? ((l15 & 1) ? t3 : t2)
                                   : ((l15 & 1) ? t1 : t0);

        #pragma unroll
        for (int kt = 0; kt < 4; ++kt) {
            #pragma unroll
            for (int h = 0; h < 2; ++h) {
                oacc[kt][h][0] += wl * av[kt][h][0];
                oacc[kt][h][1] += wl * av[kt][h][1];
                oacc[kt][h][2] += wl * av[kt][h][2];
                oacc[kt][h][3] += wl * av[kt][h][3];
            }
        }
    }

    // ---- reduce oacc over the 16 rows (l15 lanes) of each quad ----
    #pragma unroll
    for (int kt = 0; kt < 4; ++kt)
        #pragma unroll
        for (int h = 0; h < 2; ++h)
            #pragma unroll
            for (int c = 0; c < 4; ++c) {
                float v = oacc[kt][h][c];
                v += __shfl_xor(v, 1, 64);
                v += __shfl_xor(v, 2, 64);
                v += __shfl_xor(v, 4, 64);
                v += __shfl_xor(v, 8, 64);
                oacc[kt][h][c] = v;
            }

    if (l15 == 0) {
        #pragma unroll
        for (int kt = 0; kt < 4; ++kt) {
            *(f32x4*)&red[wave * 128 + kt * 32 + quad * 8]     = oacc[kt][0];
            *(f32x4*)&red[wave * 128 + kt * 32 + quad * 8 + 4] = oacc[kt][1];
        }
    }
    __syncthreads();
    if (tid < E) {
        out[(size_t)bat * E + tid] =
            red[tid] + red[128 + tid] + red[256 + tid] + red[384 + tid];
    }
}

extern "C" void kernel_launch(void* const* d_in, const int* in_sizes, int n_in,
                              void* d_out, int out_size, void* d_ws, size_t ws_size,
                              hipStream_t stream) {
    const float* behaviors = (const float*)d_in[0];
    const float* target    = (const float*)d_in[1];
    const float* W1        = (const float*)d_in[2];
    const float* b1        = (const float*)d_in[3];
    const float* W2        = (const float*)d_in[4];
    const float* b2        = (const float*)d_in[5];
    float* out = (float*)d_out;

    hipLaunchKernelGGL(attn_fused, dim3(2048), dim3(256), 0, stream,
                       behaviors, target, W1, b1, W2, b2, out);
}